// Round 6
// baseline (5132.093 us; speedup 1.0000x reference)
//
#include <hip/hip_runtime.h>
#include <math.h>

// SynchronGRU R12 (resubmit; R5 bench was a broker acquisition timeout, no data).
// MFMA the x-GEMM (bf16x3 split precision), keep fp32 h-dot.
// R11 post-mortem: VGPR 84 clean, VALU 71%, but ~500 LDS instr/step (X2's
// x/w reads at 3.2 FMA/read + 192 h broadcasts) serialize on the one LDS
// pipe -> 5760 cy/step vs 1536 VALU floor. MfmaUtil = 0 while X2 is a clean
// GEMM (M=32 = 2 rows x 16 steps, K=128, N=384).
// R12: x-projection via v_mfma_f32_16x16x32_bf16 with split precision:
// f = hi(bf16) + lo(bf16); D += Ahi*Bhi + Ahi*Blo + Alo*Bhi => ~2^-16 rel.
// Layout safety: A and B frags both packed with the SAME k-enumeration
// (k = (lane>>4)*8 + e); MFMA contraction is invariant to a common k-perm.
// C/D: col = lane&15, row = (lane>>4)*4 + reg (HW-verified). Biases folded
// into C-init (z,r get x+h bias; cand gets x bias). W_x staged per 32-k tile
// as packed bf16 hi/lo fragments in LDS (scatter on stage, b128 on read).
// xstage row stride padded 128->132 to break 16-way bank conflict on A reads.
// h-dot unchanged from R11 (64 resident W_h floats/thread, clean at VGPR 84).

namespace {

constexpr int kB = 512;
constexpr int kT = 256;
constexpr int kF = 8;
constexpr int kU = 128;
constexpr int kG = 384;   // 3*U, gate order [z, r, h]
constexpr int kL = 8;
constexpr int kRows = 2;       // batch rows per block
constexpr int kThreads = 768;  // 12 waves, 3 per SIMD
constexpr int kSt = 16;        // time-steps per chunk (x-GEMM M = 32)
constexpr int kXRow = 132;     // padded xstage row stride (floats)

// LDS layout (floats)
constexpr int kOffXstage = 0;                      // [32 rows][132] = 4224
constexpr int kOffWpk    = 4224;                   // 24576 u16 (bf16 hi/lo frags) = 12288
constexpr int kOffXg     = 4224 + 12288;           // [2r][16tt][384] = 12288  (16512)
constexpr int kOffHbuf   = kOffXg + 12288;         // [2][128] = 256           (28800)
constexpr int kOffPacc   = kOffHbuf + 256;         // [4kq][2r][384] = 3072    (29056)
constexpr int kOffCinit  = kOffPacc + 3072;        // [384]                    (32128)
constexpr int kOffBiash  = kOffCinit + 384;        // [384]                    (32512)
constexpr int kSmemFloats = kOffBiash + 384;       // 32896 floats = 128.5 KB
static_assert(kSmemFloats * 4 <= 160 * 1024, "LDS budget");

typedef __attribute__((ext_vector_type(8))) short short8;
typedef __attribute__((ext_vector_type(4))) float f32x4;

__device__ __forceinline__ float frcp(float x) { return __builtin_amdgcn_rcpf(x); }

// split 8 fp32 (two float4, consecutive k) into bf16-hi / bf16-lo fragments
__device__ __forceinline__ void split8(const float4 a, const float4 b,
                                       short8& hi, short8& lo) {
    union { unsigned u[4]; short8 v; } H, L;
    const float f[8] = {a.x, a.y, a.z, a.w, b.x, b.y, b.z, b.w};
#pragma unroll
    for (int i = 0; i < 4; ++i) {
        const unsigned u0 = __float_as_uint(f[2 * i]);
        const unsigned u1 = __float_as_uint(f[2 * i + 1]);
        H.u[i] = (u0 >> 16) | (u1 & 0xFFFF0000u);
        const float r0 = f[2 * i]     - __uint_as_float(u0 & 0xFFFF0000u);
        const float r1 = f[2 * i + 1] - __uint_as_float(u1 & 0xFFFF0000u);
        L.u[i] = (__float_as_uint(r0) >> 16) | (__float_as_uint(r1) & 0xFFFF0000u);
    }
    hi = H.v; lo = L.v;
}

#define MFMA3(C, Ahi, Alo, Bhi, Blo)                                          \
    C = __builtin_amdgcn_mfma_f32_16x16x32_bf16((Ahi), (Bhi), C, 0, 0, 0);    \
    C = __builtin_amdgcn_mfma_f32_16x16x32_bf16((Ahi), (Blo), C, 0, 0, 0);    \
    C = __builtin_amdgcn_mfma_f32_16x16x32_bf16((Alo), (Bhi), C, 0, 0, 0);

__global__ __launch_bounds__(kThreads, 3) void gru_all(
    const float* __restrict__ xin,      // (B,T,F)
    const float* __restrict__ init_h,   // (L,B,U)
    const float* __restrict__ kernel0,  // (F,3U)
    const float* __restrict__ kernels,  // (L-1,U,3U)
    const float* __restrict__ rec_k,    // (L,U,3U)
    const float* __restrict__ biases,   // (L,2,3U)
    float* __restrict__ out)            // (B,T,U) seq out | (L,B,U) states
{
    __shared__ __align__(16) float smem[kSmemFloats];
    float* xstage = smem + kOffXstage;
    float* Wpk    = smem + kOffWpk;
    float* xg     = smem + kOffXg;
    float* hbuf   = smem + kOffHbuf;
    float* pacc   = smem + kOffPacc;
    float* cinit  = smem + kOffCinit;
    float* biash  = smem + kOffBiash;

    const int tid  = threadIdx.x;
    const int b0   = blockIdx.x * kRows;
    const int lane = tid & 63;
    const int wv   = tid >> 6;
    const int ln15 = lane & 15;
    const int lh   = lane >> 4;
    // h-dot identity (R11): wave-uniform k-quarter, cols {ch, 192+ch}
    const int kq = wv & 3;
    const int ch = ((wv >> 2) << 6) + lane;  // 0..191
    // x-MFMA identity: wave owns N-tiles {2wv, 2wv+1}
    const int ntA = 2 * wv, ntB = 2 * wv + 1;
    // gate identity (valid tid<256)
    const int gr = (tid >> 7) & 1;
    const int gu = tid & 127;

    float* __restrict__ buf    = out;                        // in-place activations
    float* __restrict__ states = out + (size_t)kB * kT * kU; // final h per layer

    // zero xstage once: layer 0 writes only k 0..7; rest must be 0.
    for (int j = tid; j < 32 * kXRow; j += kThreads) xstage[j] = 0.f;

#pragma unroll 1
    for (int l = 0; l < kL; ++l) {
        // ---- W_h -> registers (once per layer): 64 floats/thread ----
        float whA[32], whB[32];
        {
            const float* Wh = rec_k + (size_t)l * kU * kG;
#pragma unroll
            for (int i = 0; i < 32; ++i) {
                const float* p = Wh + (size_t)(32 * kq + i) * kG;
                whA[i] = p[ch]; whB[i] = p[192 + ch];
            }
        }
        // biases: cinit = biasx + (col<256 ? biash : 0) folded into MFMA C-init
        if (tid < kG) {
            const float bx = biases[(size_t)l * 2 * kG + tid];
            const float bh = biases[(size_t)l * 2 * kG + kG + tid];
            cinit[tid] = bx + (tid < 2 * kU ? bh : 0.f);
            biash[tid] = bh;
        }
        if (tid < kRows * kU)
            hbuf[tid] = init_h[(size_t)l * kB * kU + (size_t)(b0 + gr) * kU + gu];
        __syncthreads();

        const int nkt = (l == 0) ? 1 : 4;  // 32-k tiles (l0: K=8, zero-padded)

#pragma unroll 1
        for (int t0 = 0; t0 < kT; t0 += kSt) {
            // ---- X1: stage x for the next 16 steps (padded rows) ----
            if (l == 0) {
                if (tid < 64) {
                    const int r = tid >> 5, q = tid & 31, tt = q >> 1, hf = q & 1;
                    *(float4*)&xstage[(r * kSt + tt) * kXRow + 4 * hf] =
                        *(const float4*)(xin + ((size_t)(b0 + r) * kT + (t0 + tt)) * kF + 4 * hf);
                }
            } else {
#pragma unroll
                for (int i = tid; i < 1024; i += kThreads) {
                    const int r = i >> 9, idx = i & 511, tt = idx >> 5, c4 = idx & 31;
                    *(float4*)&xstage[(r * kSt + tt) * kXRow + 4 * c4] =
                        *(const float4*)(buf + ((size_t)(b0 + r) * kT + (t0 + tt)) * kU + 4 * c4);
                }
            }

            // ---- X2: x-GEMM via MFMA (bf16x3), biases folded into C-init ----
            {
                const float ciA = cinit[ntA * 16 + ln15];
                const float ciB = cinit[ntB * 16 + ln15];
                f32x4 C00 = {ciA, ciA, ciA, ciA};  // [mt=0][ntA]
                f32x4 C10 = {ciA, ciA, ciA, ciA};  // [mt=1][ntA]
                f32x4 C01 = {ciB, ciB, ciB, ciB};  // [mt=0][ntB]
                f32x4 C11 = {ciB, ciB, ciB, ciB};  // [mt=1][ntB]

#pragma unroll 1
                for (int kt = 0; kt < nkt; ++kt) {
                    __syncthreads();  // Wpk free (prev readers done) + xstage ready
                    // stage W_x k-tile as packed bf16 hi/lo fragments
                    {
                        const float* Wxp = (l == 0)
                            ? kernel0
                            : kernels + (size_t)(l - 1) * kU * kG + (size_t)kt * 32 * kG;
                        asm volatile("" : "+v"(Wxp));  // no LICM hoist across t0
                        unsigned short* wp = (unsigned short*)Wpk;
#pragma unroll
                        for (int j = 0; j < 4; ++j) {
                            const int lin = tid + j * kThreads;   // 0..3071
                            const int row = lin / 96;             // k in tile, 0..31
                            const int c4  = lin % 96;
                            float4 w = {0.f, 0.f, 0.f, 0.f};
                            if (l != 0 || row < kF)
                                w = *(const float4*)(Wxp + (size_t)row * kG + 4 * c4);
                            const int lh16 = (row >> 3) * 16;
                            const int eo   = row & 7;
                            const float wf[4] = {w.x, w.y, w.z, w.w};
#pragma unroll
                            for (int e4 = 0; e4 < 4; ++e4) {
                                const int cc = 4 * c4 + e4;
                                const int nt = cc >> 4;
                                const int ls = lh16 + (cc & 15);
                                const unsigned u = __float_as_uint(wf[e4]);
                                const float rf = wf[e4] - __uint_as_float(u & 0xFFFF0000u);
                                wp[((nt * 2 + 0) * 64 + ls) * 8 + eo] =
                                    (unsigned short)(u >> 16);
                                wp[((nt * 2 + 1) * 64 + ls) * 8 + eo] =
                                    (unsigned short)(__float_as_uint(rf) >> 16);
                            }
                        }
                    }
                    __syncthreads();

                    // A-fragments from xstage (k = kt*32 + lh*8 + e)
                    const float4* xs4 = (const float4*)xstage;
                    const int fi0 = (0 * 16 + ln15) * (kXRow / 4) + kt * 8 + lh * 2;
                    const int fi1 = (1 * 16 + ln15) * (kXRow / 4) + kt * 8 + lh * 2;
                    short8 Ahi0, Alo0, Ahi1, Alo1;
                    split8(xs4[fi0], xs4[fi0 + 1], Ahi0, Alo0);
                    split8(xs4[fi1], xs4[fi1 + 1], Ahi1, Alo1);

                    // B-fragments (pre-packed) + 3-term MFMAs
                    const short8* Bp = (const short8*)Wpk;
                    const short8 BhiA = Bp[(ntA * 2 + 0) * 64 + lane];
                    const short8 BloA = Bp[(ntA * 2 + 1) * 64 + lane];
                    const short8 BhiB = Bp[(ntB * 2 + 0) * 64 + lane];
                    const short8 BloB = Bp[(ntB * 2 + 1) * 64 + lane];
                    MFMA3(C00, Ahi0, Alo0, BhiA, BloA)
                    MFMA3(C10, Ahi1, Alo1, BhiA, BloA)
                    MFMA3(C01, Ahi0, Alo0, BhiB, BloB)
                    MFMA3(C11, Ahi1, Alo1, BhiB, BloB)
                }

                // write xg: D row = (lh*4 + reg) -> tt; Mtile -> batch row
#pragma unroll
                for (int reg = 0; reg < 4; ++reg) {
                    const int ml = lh * 4 + reg;
                    xg[(0 * kSt + ml) * kG + ntA * 16 + ln15] = C00[reg];
                    xg[(1 * kSt + ml) * kG + ntA * 16 + ln15] = C10[reg];
                    xg[(0 * kSt + ml) * kG + ntB * 16 + ln15] = C01[reg];
                    xg[(1 * kSt + ml) * kG + ntB * 16 + ln15] = C11[reg];
                }
            }
            __syncthreads();

            // ---- 16 recurrence steps: register W_h + LDS broadcasts ----
#pragma unroll 1
            for (int tt = 0; tt < kSt; ++tt) {
                {
                    const float4* hs0 = (const float4*)&hbuf[32 * kq];
                    const float4* hs1 = (const float4*)&hbuf[kU + 32 * kq];
                    float a0A = 0.f, a0B = 0.f, a1A = 0.f, a1B = 0.f;
#pragma unroll
                    for (int k4 = 0; k4 < 8; ++k4) {
                        const float4 h0 = hs0[k4];
                        const float4 h1 = hs1[k4];
                        a0A += whA[4 * k4 + 0] * h0.x; a0B += whB[4 * k4 + 0] * h0.x;
                        a1A += whA[4 * k4 + 0] * h1.x; a1B += whB[4 * k4 + 0] * h1.x;
                        a0A += whA[4 * k4 + 1] * h0.y; a0B += whB[4 * k4 + 1] * h0.y;
                        a1A += whA[4 * k4 + 1] * h1.y; a1B += whB[4 * k4 + 1] * h1.y;
                        a0A += whA[4 * k4 + 2] * h0.z; a0B += whB[4 * k4 + 2] * h0.z;
                        a1A += whA[4 * k4 + 2] * h1.z; a1B += whB[4 * k4 + 2] * h1.z;
                        a0A += whA[4 * k4 + 3] * h0.w; a0B += whB[4 * k4 + 3] * h0.w;
                        a1A += whA[4 * k4 + 3] * h1.w; a1B += whB[4 * k4 + 3] * h1.w;
                    }
                    pacc[(kq * 2 + 0) * kG + ch]       = a0A;
                    pacc[(kq * 2 + 0) * kG + 192 + ch] = a0B;
                    pacc[(kq * 2 + 1) * kG + ch]       = a1A;
                    pacc[(kq * 2 + 1) * kG + 192 + ch] = a1B;
                }
                __syncthreads();

                // ---- gates: threads 0..255 = (row, unit); biases pre-folded ----
                if (tid < kRows * kU) {
                    const float* xgp = &xg[(size_t)(gr * kSt + tt) * kG];
                    float sz = 0.f, sr = 0.f, sp = 0.f;
#pragma unroll
                    for (int k2 = 0; k2 < 4; ++k2) {
                        const float* ph = pacc + (size_t)(k2 * 2 + gr) * kG;
                        sz += ph[gu]; sr += ph[kU + gu]; sp += ph[2 * kU + gu];
                    }
                    const float z  = frcp(1.f + __expf(-(xgp[gu] + sz)));
                    const float rg = frcp(1.f + __expf(-(xgp[kU + gu] + sr)));
                    const float ta = xgp[2 * kU + gu] + rg * (sp + biash[2 * kU + gu]);
                    const float hh = 1.f - 2.f * frcp(1.f + __expf(2.f * ta));  // tanh
                    const float h  = z * hbuf[tid] + (1.f - z) * hh;
                    hbuf[tid] = h;
                    buf[((size_t)(b0 + gr) * kT + (t0 + tt)) * kU + gu] = h;
                }
                __syncthreads();
            }
        }

        // ---- final state of this layer ----
        if (tid < kRows * kU)
            states[(size_t)l * kB * kU + (size_t)(b0 + gr) * kU + gu] = hbuf[tid];
        __syncthreads();
    }
}

}  // namespace

extern "C" void kernel_launch(void* const* d_in, const int* in_sizes, int n_in,
                              void* d_out, int out_size, void* d_ws, size_t ws_size,
                              hipStream_t stream) {
    const float* xin     = (const float*)d_in[0];
    const float* init_h  = (const float*)d_in[1];
    const float* kernel0 = (const float*)d_in[2];
    const float* kernels = (const float*)d_in[3];
    const float* rec_k   = (const float*)d_in[4];
    const float* biases  = (const float*)d_in[5];
    float* out = (float*)d_out;

    dim3 grid(kB / kRows);   // 256 blocks, 1 per CU (128.5 KB LDS enforces)
    dim3 block(kThreads);    // 768 threads = 12 waves, 3 per SIMD
    gru_all<<<grid, block, 0, stream>>>(xin, init_h, kernel0, kernels, rec_k, biases, out);
}

// Round 7
// 2484.895 us; speedup vs baseline: 2.0653x; 2.0653x over previous
//
#include <hip/hip_runtime.h>
#include <math.h>

// SynchronGRU R13: keep MFMA x-GEMM, kill the B-staging LDS scatter.
// R12 post-mortem: MFMA path works (MfmaUtil 2.2%, correct), but the W-pack
// scatter (24576 ds_write_b16/k-tile at 64B lane stride -> ~32-way conflicts)
// cost SQ_LDS_BANK_CONFLICT = 1.4e9 cycles (~2.3 ms/CU) -> net regression
// 4.9 -> 5.27 ms. Fix: B fragments are per-lane-local (col = nt*16+(lane&15),
// k = kt*32+(lane>>4)*8+eo), so each lane loads its 8 weights DIRECTLY from
// global (16-lane groups read 16 consecutive floats = coalesced 64B, L2-hit)
// and hi/lo-packs in registers. Deletes Wpk (-48 KB LDS), the scatter, the
// pack pass, and both barriers per k-tile (X2 k-loop is now barrier-free).
// W_x L2 traffic unchanged (196 KB/block/chunk; launder prevents LICM from
// making 128 packed W_x regs resident on top of W_h -- R10 scratch lesson).
// h-dot (fp32, 64 resident W_h floats/thread) and gate phase unchanged.

namespace {

constexpr int kB = 512;
constexpr int kT = 256;
constexpr int kF = 8;
constexpr int kU = 128;
constexpr int kG = 384;   // 3*U, gate order [z, r, h]
constexpr int kL = 8;
constexpr int kRows = 2;       // batch rows per block
constexpr int kThreads = 768;  // 12 waves, 3 per SIMD
constexpr int kSt = 16;        // time-steps per chunk (x-GEMM M = 32)
constexpr int kXRow = 132;     // padded xstage row stride (floats)

// LDS layout (floats)
constexpr int kOffXstage = 0;                      // [32 rows][132] = 4224
constexpr int kOffXg     = 4224;                   // [2r][16tt][384] = 12288 (4224)
constexpr int kOffHbuf   = 4224 + 12288;           // [2][128] = 256   (16512)
constexpr int kOffPacc   = kOffHbuf + 256;         // [4kq][2r][384] = 3072 (16768)
constexpr int kOffCinit  = kOffPacc + 3072;        // [384] (19840)
constexpr int kOffBiash  = kOffCinit + 384;        // [384] (20224)
constexpr int kSmemFloats = kOffBiash + 384;       // 20608 floats = 80.5 KB
static_assert(kSmemFloats * 4 <= 160 * 1024, "LDS budget");

typedef __attribute__((ext_vector_type(8))) short short8;
typedef __attribute__((ext_vector_type(4))) float f32x4;

__device__ __forceinline__ float frcp(float x) { return __builtin_amdgcn_rcpf(x); }

// split 8 fp32 (two float4, consecutive k) into bf16-hi / bf16-lo fragments
__device__ __forceinline__ void split8(const float4 a, const float4 b,
                                       short8& hi, short8& lo) {
    union { unsigned u[4]; short8 v; } H, L;
    const float f[8] = {a.x, a.y, a.z, a.w, b.x, b.y, b.z, b.w};
#pragma unroll
    for (int i = 0; i < 4; ++i) {
        const unsigned u0 = __float_as_uint(f[2 * i]);
        const unsigned u1 = __float_as_uint(f[2 * i + 1]);
        H.u[i] = (u0 >> 16) | (u1 & 0xFFFF0000u);
        const float r0 = f[2 * i]     - __uint_as_float(u0 & 0xFFFF0000u);
        const float r1 = f[2 * i + 1] - __uint_as_float(u1 & 0xFFFF0000u);
        L.u[i] = (__float_as_uint(r0) >> 16) | (__float_as_uint(r1) & 0xFFFF0000u);
    }
    hi = H.v; lo = L.v;
}

// pack 8 scalars (array, statically unrolled) into bf16 hi/lo fragments
__device__ __forceinline__ void pack8(const float* f, short8& hi, short8& lo) {
    union { unsigned u[4]; short8 v; } H, L;
#pragma unroll
    for (int i = 0; i < 4; ++i) {
        const unsigned u0 = __float_as_uint(f[2 * i]);
        const unsigned u1 = __float_as_uint(f[2 * i + 1]);
        H.u[i] = (u0 >> 16) | (u1 & 0xFFFF0000u);
        const float r0 = f[2 * i]     - __uint_as_float(u0 & 0xFFFF0000u);
        const float r1 = f[2 * i + 1] - __uint_as_float(u1 & 0xFFFF0000u);
        L.u[i] = (__float_as_uint(r0) >> 16) | (__float_as_uint(r1) & 0xFFFF0000u);
    }
    hi = H.v; lo = L.v;
}

#define MFMA3(C, Ahi, Alo, Bhi, Blo)                                          \
    C = __builtin_amdgcn_mfma_f32_16x16x32_bf16((Ahi), (Bhi), C, 0, 0, 0);    \
    C = __builtin_amdgcn_mfma_f32_16x16x32_bf16((Ahi), (Blo), C, 0, 0, 0);    \
    C = __builtin_amdgcn_mfma_f32_16x16x32_bf16((Alo), (Bhi), C, 0, 0, 0);

__global__ __launch_bounds__(kThreads, 3) void gru_all(
    const float* __restrict__ xin,      // (B,T,F)
    const float* __restrict__ init_h,   // (L,B,U)
    const float* __restrict__ kernel0,  // (F,3U)
    const float* __restrict__ kernels,  // (L-1,U,3U)
    const float* __restrict__ rec_k,    // (L,U,3U)
    const float* __restrict__ biases,   // (L,2,3U)
    float* __restrict__ out)            // (B,T,U) seq out | (L,B,U) states
{
    __shared__ __align__(16) float smem[kSmemFloats];
    float* xstage = smem + kOffXstage;
    float* xg     = smem + kOffXg;
    float* hbuf   = smem + kOffHbuf;
    float* pacc   = smem + kOffPacc;
    float* cinit  = smem + kOffCinit;
    float* biash  = smem + kOffBiash;

    const int tid  = threadIdx.x;
    const int b0   = blockIdx.x * kRows;
    const int lane = tid & 63;
    const int wv   = tid >> 6;
    const int ln15 = lane & 15;
    const int lh   = lane >> 4;
    // h-dot identity: wave-uniform k-quarter, cols {ch, 192+ch}
    const int kq = wv & 3;
    const int ch = ((wv >> 2) << 6) + lane;  // 0..191
    // x-MFMA identity: wave owns N-tiles {2wv, 2wv+1}
    const int ntA = 2 * wv, ntB = 2 * wv + 1;
    // gate identity (valid tid<256)
    const int gr = (tid >> 7) & 1;
    const int gu = tid & 127;

    float* __restrict__ buf    = out;                        // in-place activations
    float* __restrict__ states = out + (size_t)kB * kT * kU; // final h per layer

    // zero xstage once: layer 0 writes only k 0..7; rest must be 0.
    for (int j = tid; j < 32 * kXRow; j += kThreads) xstage[j] = 0.f;

#pragma unroll 1
    for (int l = 0; l < kL; ++l) {
        // ---- W_h -> registers (once per layer): 64 floats/thread ----
        float whA[32], whB[32];
        {
            const float* Wh = rec_k + (size_t)l * kU * kG;
#pragma unroll
            for (int i = 0; i < 32; ++i) {
                const float* p = Wh + (size_t)(32 * kq + i) * kG;
                whA[i] = p[ch]; whB[i] = p[192 + ch];
            }
        }
        // biases: cinit = biasx + (col<256 ? biash : 0) folded into MFMA C-init
        if (tid < kG) {
            const float bx = biases[(size_t)l * 2 * kG + tid];
            const float bh = biases[(size_t)l * 2 * kG + kG + tid];
            cinit[tid] = bx + (tid < 2 * kU ? bh : 0.f);
            biash[tid] = bh;
        }
        if (tid < kRows * kU)
            hbuf[tid] = init_h[(size_t)l * kB * kU + (size_t)(b0 + gr) * kU + gu];
        __syncthreads();

        const int nkt = (l == 0) ? 1 : 4;  // 32-k tiles (l0: K=8, zero-padded)

#pragma unroll 1
        for (int t0 = 0; t0 < kT; t0 += kSt) {
            // ---- X1: stage x for the next 16 steps (padded rows) ----
            if (l == 0) {
                if (tid < 64) {
                    const int r = tid >> 5, q = tid & 31, tt = q >> 1, hf = q & 1;
                    *(float4*)&xstage[(r * kSt + tt) * kXRow + 4 * hf] =
                        *(const float4*)(xin + ((size_t)(b0 + r) * kT + (t0 + tt)) * kF + 4 * hf);
                }
            } else {
#pragma unroll
                for (int i = tid; i < 1024; i += kThreads) {
                    const int r = i >> 9, idx = i & 511, tt = idx >> 5, c4 = idx & 31;
                    *(float4*)&xstage[(r * kSt + tt) * kXRow + 4 * c4] =
                        *(const float4*)(buf + ((size_t)(b0 + r) * kT + (t0 + tt)) * kU + 4 * c4);
                }
            }
            __syncthreads();

            // ---- X2: x-GEMM via MFMA; B frags loaded per-lane from global ----
            {
                const float ciA = cinit[ntA * 16 + ln15];
                const float ciB = cinit[ntB * 16 + ln15];
                f32x4 C00 = {ciA, ciA, ciA, ciA};  // [mt=0][ntA]
                f32x4 C10 = {ciA, ciA, ciA, ciA};  // [mt=1][ntA]
                f32x4 C01 = {ciB, ciB, ciB, ciB};  // [mt=0][ntB]
                f32x4 C11 = {ciB, ciB, ciB, ciB};  // [mt=1][ntB]

                const float* Wxp = (l == 0) ? kernel0
                                            : kernels + (size_t)(l - 1) * kU * kG;
                asm volatile("" : "+v"(Wxp));  // no LICM hoist across t0 loop

#pragma unroll 1
                for (int kt = 0; kt < nkt; ++kt) {
                    // B fragments: lane loads its 8 weights (col = nt*16+ln15,
                    // k = kt*32 + lh*8 + eo); 16-lane groups -> coalesced 64B.
                    float fA[8], fB[8];
#pragma unroll
                    for (int eo = 0; eo < 8; ++eo) {
                        const int row = kt * 32 + lh * 8 + eo;
                        float vA = 0.f, vB = 0.f;
                        if (l != 0 || row < kF) {
                            const float* rp = Wxp + (size_t)row * kG;
                            vA = rp[ntA * 16 + ln15];
                            vB = rp[ntB * 16 + ln15];
                        }
                        fA[eo] = vA; fB[eo] = vB;
                    }
                    short8 BhiA, BloA, BhiB, BloB;
                    pack8(fA, BhiA, BloA);
                    pack8(fB, BhiB, BloB);

                    // A-fragments from xstage (k = kt*32 + lh*8 + e)
                    const float4* xs4 = (const float4*)xstage;
                    const int fi0 = (0 * 16 + ln15) * (kXRow / 4) + kt * 8 + lh * 2;
                    const int fi1 = (1 * 16 + ln15) * (kXRow / 4) + kt * 8 + lh * 2;
                    short8 Ahi0, Alo0, Ahi1, Alo1;
                    split8(xs4[fi0], xs4[fi0 + 1], Ahi0, Alo0);
                    split8(xs4[fi1], xs4[fi1 + 1], Ahi1, Alo1);

                    MFMA3(C00, Ahi0, Alo0, BhiA, BloA)
                    MFMA3(C10, Ahi1, Alo1, BhiA, BloA)
                    MFMA3(C01, Ahi0, Alo0, BhiB, BloB)
                    MFMA3(C11, Ahi1, Alo1, BhiB, BloB)
                }

                // write xg: D row = (lh*4 + reg) -> tt; Mtile -> batch row
#pragma unroll
                for (int reg = 0; reg < 4; ++reg) {
                    const int ml = lh * 4 + reg;
                    xg[(0 * kSt + ml) * kG + ntA * 16 + ln15] = C00[reg];
                    xg[(1 * kSt + ml) * kG + ntA * 16 + ln15] = C10[reg];
                    xg[(0 * kSt + ml) * kG + ntB * 16 + ln15] = C01[reg];
                    xg[(1 * kSt + ml) * kG + ntB * 16 + ln15] = C11[reg];
                }
            }
            __syncthreads();

            // ---- 16 recurrence steps: register W_h + LDS broadcasts ----
#pragma unroll 1
            for (int tt = 0; tt < kSt; ++tt) {
                {
                    const float4* hs0 = (const float4*)&hbuf[32 * kq];
                    const float4* hs1 = (const float4*)&hbuf[kU + 32 * kq];
                    float a0A = 0.f, a0B = 0.f, a1A = 0.f, a1B = 0.f;
#pragma unroll
                    for (int k4 = 0; k4 < 8; ++k4) {
                        const float4 h0 = hs0[k4];
                        const float4 h1 = hs1[k4];
                        a0A += whA[4 * k4 + 0] * h0.x; a0B += whB[4 * k4 + 0] * h0.x;
                        a1A += whA[4 * k4 + 0] * h1.x; a1B += whB[4 * k4 + 0] * h1.x;
                        a0A += whA[4 * k4 + 1] * h0.y; a0B += whB[4 * k4 + 1] * h0.y;
                        a1A += whA[4 * k4 + 1] * h1.y; a1B += whB[4 * k4 + 1] * h1.y;
                        a0A += whA[4 * k4 + 2] * h0.z; a0B += whB[4 * k4 + 2] * h0.z;
                        a1A += whA[4 * k4 + 2] * h1.z; a1B += whB[4 * k4 + 2] * h1.z;
                        a0A += whA[4 * k4 + 3] * h0.w; a0B += whB[4 * k4 + 3] * h0.w;
                        a1A += whA[4 * k4 + 3] * h1.w; a1B += whB[4 * k4 + 3] * h1.w;
                    }
                    pacc[(kq * 2 + 0) * kG + ch]       = a0A;
                    pacc[(kq * 2 + 0) * kG + 192 + ch] = a0B;
                    pacc[(kq * 2 + 1) * kG + ch]       = a1A;
                    pacc[(kq * 2 + 1) * kG + 192 + ch] = a1B;
                }
                __syncthreads();

                // ---- gates: threads 0..255 = (row, unit); biases pre-folded ----
                if (tid < kRows * kU) {
                    const float* xgp = &xg[(size_t)(gr * kSt + tt) * kG];
                    float sz = 0.f, sr = 0.f, sp = 0.f;
#pragma unroll
                    for (int k2 = 0; k2 < 4; ++k2) {
                        const float* ph = pacc + (size_t)(k2 * 2 + gr) * kG;
                        sz += ph[gu]; sr += ph[kU + gu]; sp += ph[2 * kU + gu];
                    }
                    const float z  = frcp(1.f + __expf(-(xgp[gu] + sz)));
                    const float rg = frcp(1.f + __expf(-(xgp[kU + gu] + sr)));
                    const float ta = xgp[2 * kU + gu] + rg * (sp + biash[2 * kU + gu]);
                    const float hh = 1.f - 2.f * frcp(1.f + __expf(2.f * ta));  // tanh
                    const float h  = z * hbuf[tid] + (1.f - z) * hh;
                    hbuf[tid] = h;
                    buf[((size_t)(b0 + gr) * kT + (t0 + tt)) * kU + gu] = h;
                }
                __syncthreads();
            }
        }

        // ---- final state of this layer ----
        if (tid < kRows * kU)
            states[(size_t)l * kB * kU + (size_t)(b0 + gr) * kU + gu] = hbuf[tid];
        __syncthreads();
    }
}

}  // namespace

extern "C" void kernel_launch(void* const* d_in, const int* in_sizes, int n_in,
                              void* d_out, int out_size, void* d_ws, size_t ws_size,
                              hipStream_t stream) {
    const float* xin     = (const float*)d_in[0];
    const float* init_h  = (const float*)d_in[1];
    const float* kernel0 = (const float*)d_in[2];
    const float* kernels = (const float*)d_in[3];
    const float* rec_k   = (const float*)d_in[4];
    const float* biases  = (const float*)d_in[5];
    float* out = (float*)d_out;

    dim3 grid(kB / kRows);   // 256 blocks, 1 per CU
    dim3 block(kThreads);    // 768 threads = 12 waves, 3 per SIMD
    gru_all<<<grid, block, 0, stream>>>(xin, init_h, kernel0, kernels, rec_k, biases, out);
}